// Round 2
// baseline (2697.215 us; speedup 1.0000x reference)
//
#include <hip/hip_runtime.h>

// ---------------- constants ----------------
#define BWIN 2048
#define NKV  49      // kv rows per window
#define DIM  384
#define NH   12
#define HD   32
#define QN   196     // q rows per window
#define KQ   192     // q input width (DIM/CS)
#define SCALE 0.17677669529663687f

// LDS (u16 elements), total 34416 el = 68832 B  -> 2 blocks/CU
//   bias[169*12] @0 (padded to 2032)
//   union @2032 (phase-ordered, barrier-separated):
//     phase0/1 : kvs[49][392] = 19208 el
//     transpose: 6 waves x (K[49][40]=1960 + V^T[32][72]=2304) = 25584 el (2 rounds)
//     phase2   : qtile[16][200]=3200 | obuf[12][16][40]=7680 | qp[12][16][40]=7680 | P[12][16][72]=13824
#define OFF_U   2032
#define UNI_SZ  32384
#define LDS_TOT (OFF_U + UNI_SZ)

#define KV_STR  392
#define QT_STR  200
#define OB_STR  40
#define QP_STR  40
#define P_STR   72
#define SCK_STR 40
#define SCV_STR 72
#define U_QT    0
#define U_OB    3200
#define U_QP    10880
#define U_P     18560

typedef __bf16 bf16x8 __attribute__((ext_vector_type(8)));
typedef float  f32x4  __attribute__((ext_vector_type(4)));
typedef unsigned short u16;
typedef unsigned int   u32;

__device__ __forceinline__ int imin(int a, int b) { return a < b ? a : b; }

__device__ __forceinline__ u16 f2b(float f) {            // fp32 -> bf16 RNE
    u32 u = __builtin_bit_cast(u32, f);
    return (u16)((u + 0x7fffu + ((u >> 16) & 1u)) >> 16);
}
__device__ __forceinline__ float b2f(u16 h) {
    return __builtin_bit_cast(float, ((u32)h) << 16);
}
__device__ __forceinline__ bf16x8 ld_frag(const u16* p) { // 16B frag load (LDS or global)
    uint4 v = *(const uint4*)p;
    return __builtin_bit_cast(bf16x8, v);
}
__device__ __forceinline__ void lds_fence() {
    asm volatile("s_waitcnt lgkmcnt(0)" ::: "memory");
}
#define MFMA(a, b, c) __builtin_amdgcn_mfma_f32_16x16x32_bf16((a), (b), (c), 0, 0, 0)

// ---------------- K0: transpose+convert weights to bf16 in ws ----------------
// ws layout (ushort elems): w_kvT[768][384] @0 ; w_qT[384][192]*SCALE @294912 ; w_projT[192][384] @368640
__global__ void prep_weights(const float* __restrict__ w_kv, const float* __restrict__ w_q,
                             const float* __restrict__ w_proj, u16* __restrict__ wbuf) {
    int i = blockIdx.x * 512 + threadIdx.x;   // grid covers exactly 442368
    if (i < 294912) {
        int n = i / 384, k = i % 384;
        wbuf[i] = f2b(w_kv[k * 768 + n]);
    } else if (i < 368640) {
        int j = i - 294912;
        int n = j / 192, k = j % 192;
        wbuf[i] = f2b(w_q[k * 384 + n] * SCALE);   // SCALE folded into w_q
    } else {
        int j = i - 368640;
        int n = j / 384, k = j % 384;
        wbuf[i] = f2b(w_proj[k * 192 + n]);
    }
}

// ---------------- fused per-window kernel: 12 waves == 12 heads, 2 blocks/CU ----------------
__global__ __launch_bounds__(768, 6) void wca_fused(
    const float* __restrict__ kv, const float* __restrict__ q,
    const float* __restrict__ b_kv, const float* __restrict__ b_q,
    const float* __restrict__ bias_table, const float* __restrict__ b_proj,
    const u16* __restrict__ wkvT, const u16* __restrict__ wqT, const u16* __restrict__ wprojT,
    float* __restrict__ out) {

    __shared__ u16 lds[LDS_TOT];

    const int tid  = threadIdx.x;
    const int b    = blockIdx.x;
    const int wave = tid >> 6, lane = tid & 63, ln = lane & 15, quad = lane >> 4;
    const int h    = wave;   // wave == head
    const int cb   = h * HD;

    u16* bias_s = lds;
    u16* uni    = lds + OFF_U;
    u16* kvs    = uni;                      // phase 0/1 only
    u16* qtile  = uni + U_QT;
    u16* obuf   = uni + U_OB;
    u16* qp_s   = uni + U_QP + h * (16 * QP_STR);  // wave-private
    u16* P_s    = uni + U_P  + h * (16 * P_STR);   // wave-private

    // ---- phase 0: stage kv (49x384 fp32->bf16) + bias table ----
    {
        const float4* src = (const float4*)(kv + (size_t)b * NKV * DIM);
        for (int c = tid; c < NKV * DIM / 4; c += 768) {
            int r = c / (DIM / 4), c4 = c % (DIM / 4);
            float4 f = src[c];
            ushort4 u; u.x = f2b(f.x); u.y = f2b(f.y); u.z = f2b(f.z); u.w = f2b(f.w);
            *(ushort4*)&kvs[r * KV_STR + c4 * 4] = u;
        }
        for (int c = tid; c < 169 * NH; c += 768) bias_s[c] = f2b(bias_table[c]);
    }
    __syncthreads();

    // ---- phase 1: kvp for head h (M=49 pad 64, N=64 {K|V}, K=384); one wave per head ----
    f32x4 acc[4][4];   // [col group: 0=K ln,1=K 16+ln,2=V ln,3=V 16+ln][m: kk tile]
#pragma unroll
    for (int j = 0; j < 4; j++)
#pragma unroll
        for (int m = 0; m < 4; m++) acc[j][m] = (f32x4){0.f, 0.f, 0.f, 0.f};
    {
        const u16* ar[4] = {
            &kvs[imin(ln,      NKV - 1) * KV_STR + quad * 8],
            &kvs[imin(16 + ln, NKV - 1) * KV_STR + quad * 8],
            &kvs[imin(32 + ln, NKV - 1) * KV_STR + quad * 8],
            &kvs[imin(48 + ln, NKV - 1) * KV_STR + quad * 8] };
#pragma unroll 1
        for (int half = 0; half < 2; ++half) {     // half 0: K cols; half 1: V cols
            const u16* w0 = wkvT + (size_t)(half * DIM + cb + ln) * DIM + quad * 8;
            const u16* w1 = wkvT + (size_t)(half * DIM + cb + 16 + ln) * DIM + quad * 8;
#pragma unroll
            for (int k = 0; k < 12; k++) {
                bf16x8 b0 = ld_frag(w0 + k * 32);
                bf16x8 b1 = ld_frag(w1 + k * 32);
#pragma unroll
                for (int m = 0; m < 4; m++) {
                    bf16x8 a = ld_frag(ar[m] + k * 32);
                    acc[half * 2 + 0][m] = MFMA(a, b0, acc[half * 2 + 0][m]);
                    acc[half * 2 + 1][m] = MFMA(a, b1, acc[half * 2 + 1][m]);
                }
            }
        }
    }
    __syncthreads();   // kvs dead; union becomes transpose scratch

    // ---- phase 1.5: C-layout -> B-frag transpose via per-wave scratch (2 rounds of 6 waves) ----
    bf16x8 bk[4];    // K frags: frag[ln=kk][elem=d]  (resident all of phase 2)
    bf16x8 bvf[4];   // V^T frags [dt*2+kt]: frag[ln=d][elem=kk]
    {
        const float bk0 = b_kv[cb + ln],       bk1 = b_kv[cb + 16 + ln];
        const float bv0 = b_kv[DIM + cb + ln], bv1 = b_kv[DIM + cb + 16 + ln];
#pragma unroll 1
        for (int rnd = 0; rnd < 2; ++rnd) {
            if (wave / 6 == rnd) {
                u16* scK = uni + (wave - rnd * 6) * (1960 + 2304);
                u16* scV = scK + 1960;
                for (int i = lane; i < HD * SCV_STR; i += 64) scV[i] = 0;  // zero kk pad (avoid NaN*0)
#pragma unroll
                for (int m = 0; m < 4; m++)
#pragma unroll
                    for (int r = 0; r < 4; r++) {
                        int kk = m * 16 + quad * 4 + r;
                        if (kk < NKV) {
                            scK[kk * SCK_STR + ln]        = f2b(acc[0][m][r] + bk0);
                            scK[kk * SCK_STR + 16 + ln]   = f2b(acc[1][m][r] + bk1);
                            scV[ln * SCV_STR + kk]        = f2b(acc[2][m][r] + bv0);
                            scV[(16 + ln) * SCV_STR + kk] = f2b(acc[3][m][r] + bv1);
                        }
                    }
                lds_fence();
#pragma unroll
                for (int n = 0; n < 4; n++)
                    bk[n] = ld_frag(&scK[imin(n * 16 + ln, NKV - 1) * SCK_STR + quad * 8]);
#pragma unroll
                for (int dt = 0; dt < 2; dt++)
#pragma unroll
                    for (int kt = 0; kt < 2; kt++)
                        bvf[dt * 2 + kt] = ld_frag(&scV[(dt * 16 + ln) * SCV_STR + kt * 32 + quad * 8]);
            }
            __syncthreads();
        }
    }

    // ---- per-lane constants for phase 2 ----
    int kterm[4];
#pragma unroll
    for (int n = 0; n < 4; n++) {
        int kk = n * 16 + ln;
        int t4 = 4 * kk, kA = t4 / 14, kB = t4 - kA * 14;
        kterm[n] = 84 - 13 * (kA >> 1) - (kB >> 1);
    }
    const bool k3ok = (ln == 0);                       // n=3 valid only for kk==48
    const float bq0 = b_q[cb + ln] * SCALE, bq1 = b_q[cb + 16 + ln] * SCALE;
    const float bpj = b_proj[h * 16 + ln];
    const f32x4 z4 = {0.f, 0.f, 0.f, 0.f};
    const u16* wq0 = wqT + (size_t)(cb + ln) * KQ + quad * 8;
    const u16* wq1 = wqT + (size_t)(cb + 16 + ln) * KQ + quad * 8;
    const u16* wpr = wprojT + (size_t)(h * 16 + ln) * DIM + quad * 8;
    const int  rr = tid / 48, c4 = tid % 48;           // q staging assignment (16 rows x 48 float4)
    const float* qbase = q + (size_t)b * QN * KQ + c4 * 4;

    // stage q tile 0
    {
        float4 f = *(const float4*)(qbase + (size_t)imin(rr, QN - 1) * KQ);
        ushort4 u; u.x = f2b(f.x); u.y = f2b(f.y); u.z = f2b(f.z); u.w = f2b(f.w);
        *(ushort4*)&qtile[rr * QT_STR + c4 * 4] = u;
    }
    __syncthreads();

    // ---- phase 2: 13 q-row groups ----
    for (int t = 0; t < 13; ++t) {
        // prefetch next q tile into regs (LDS write deferred past PV barrier)
        float4 qn;
        if (t < 12) qn = *(const float4*)(qbase + (size_t)imin((t + 1) * 16 + rr, QN - 1) * KQ);

        // qp (M=16, N=32, K=192); w_q frags from global (L1-resident after t=0)
        f32x4 qa0 = z4, qa1 = z4;
#pragma unroll
        for (int k = 0; k < 6; k++) {
            bf16x8 a = ld_frag(&qtile[ln * QT_STR + k * 32 + quad * 8]);
            qa0 = MFMA(a, ld_frag(wq0 + k * 32), qa0);
            qa1 = MFMA(a, ld_frag(wq1 + k * 32), qa1);
        }
#pragma unroll
        for (int r = 0; r < 4; r++) {
            qp_s[(quad * 4 + r) * QP_STR + ln]      = f2b(qa0[r] + bq0);
            qp_s[(quad * 4 + r) * QP_STR + 16 + ln] = f2b(qa1[r] + bq1);
        }
        lds_fence();

        // QK^T (M=16, N=64, K=32); K frags in registers
        bf16x8 aq = ld_frag(&qp_s[ln * QP_STR + quad * 8]);
        f32x4 s[4];
#pragma unroll
        for (int n = 0; n < 4; n++) s[n] = MFMA(aq, bk[n], z4);

        // softmax (wave-private)
        float rsum[4];
#pragma unroll
        for (int r = 0; r < 4; r++) {
            int qrow = t * 16 + quad * 4 + r;
            int qb = imin(qrow, QN - 1);
            int aqd = qb / 14, bqd = qb - aqd * 14;
            int qterm = 13 * (aqd >> 1) + (bqd >> 1);
            float sv[4];
#pragma unroll
            for (int n = 0; n < 3; n++) sv[n] = s[n][r] + b2f(bias_s[(qterm + kterm[n]) * NH + h]);
            sv[3] = -1e30f;
            if (k3ok) sv[3] = s[3][r] + b2f(bias_s[(qterm + kterm[3]) * NH + h]);
            float mx = fmaxf(fmaxf(sv[0], sv[1]), fmaxf(sv[2], sv[3]));
            mx = fmaxf(mx, __shfl_xor(mx, 1));
            mx = fmaxf(mx, __shfl_xor(mx, 2));
            mx = fmaxf(mx, __shfl_xor(mx, 4));
            mx = fmaxf(mx, __shfl_xor(mx, 8));
            float e[4], sum = 0.f;
#pragma unroll
            for (int n = 0; n < 4; n++) { e[n] = __expf(sv[n] - mx); sum += e[n]; }
            sum += __shfl_xor(sum, 1);
            sum += __shfl_xor(sum, 2);
            sum += __shfl_xor(sum, 4);
            sum += __shfl_xor(sum, 8);
            rsum[r] = sum;
#pragma unroll
            for (int n = 0; n < 4; n++)
                P_s[(quad * 4 + r) * P_STR + n * 16 + ln] = f2b(e[n]);
        }
        lds_fence();

        // PV (M=16, N=32, K=64); V frags in registers
        {
            bf16x8 ap0 = ld_frag(&P_s[ln * P_STR + quad * 8]);
            bf16x8 ap1 = ld_frag(&P_s[ln * P_STR + 32 + quad * 8]);
            f32x4 o0 = MFMA(ap0, bvf[0], z4); o0 = MFMA(ap1, bvf[1], o0);
            f32x4 o1 = MFMA(ap0, bvf[2], z4); o1 = MFMA(ap1, bvf[3], o1);
#pragma unroll
            for (int r = 0; r < 4; r++) {
                float rinv = 1.0f / rsum[r];
                obuf[h * 640 + (quad * 4 + r) * OB_STR + ln]      = f2b(o0[r] * rinv);
                obuf[h * 640 + (quad * 4 + r) * OB_STR + 16 + ln] = f2b(o1[r] * rinv);
            }
        }
        __syncthreads();   // obuf visible; all qtile reads for group t done

        // write prefetched q tile (safe: qp reads finished before barrier above)
        if (t < 12) {
            ushort4 u; u.x = f2b(qn.x); u.y = f2b(qn.y); u.z = f2b(qn.z); u.w = f2b(qn.w);
            *(ushort4*)&qtile[rr * QT_STR + c4 * 4] = u;
        }

        // proj: wave h = output n-tile h (M=16, N=16, K=384 over 12 head slices)
        {
            f32x4 p0 = z4, p1 = z4;
#pragma unroll
            for (int hh = 0; hh < NH; hh += 2) {
                p0 = MFMA(ld_frag(&obuf[hh * 640 + ln * OB_STR + quad * 8]),
                          ld_frag(wpr + hh * 32), p0);
                p1 = MFMA(ld_frag(&obuf[(hh + 1) * 640 + ln * OB_STR + quad * 8]),
                          ld_frag(wpr + (hh + 1) * 32), p1);
            }
#pragma unroll
            for (int r = 0; r < 4; r++) {
                int qrow = t * 16 + quad * 4 + r;
                if (qrow < QN)
                    out[((size_t)b * QN + qrow) * KQ + h * 16 + ln] = p0[r] + p1[r] + bpj;
            }
        }
        __syncthreads();   // proj reads done; obuf/qtile reusable next group
    }
}

extern "C" void kernel_launch(void* const* d_in, const int* in_sizes, int n_in,
                              void* d_out, int out_size, void* d_ws, size_t ws_size,
                              hipStream_t stream) {
    (void)in_sizes; (void)n_in; (void)out_size; (void)ws_size;
    const float* kv         = (const float*)d_in[0];
    const float* q          = (const float*)d_in[1];
    const float* w_kv       = (const float*)d_in[2];
    const float* b_kv       = (const float*)d_in[3];
    const float* w_q        = (const float*)d_in[4];
    const float* b_q        = (const float*)d_in[5];
    const float* bias_table = (const float*)d_in[6];
    const float* w_proj     = (const float*)d_in[7];
    const float* b_proj     = (const float*)d_in[8];
    float* out = (float*)d_out;
    u16* wbuf = (u16*)d_ws;   // 442368 ushorts = 884736 B

    prep_weights<<<864, 512, 0, stream>>>(w_kv, w_q, w_proj, wbuf);
    wca_fused<<<BWIN, 768, 0, stream>>>(kv, q, b_kv, b_q, bias_table, b_proj,
                                        wbuf, wbuf + 294912, wbuf + 368640, out);
}